// Round 13
// baseline (131.282 us; speedup 1.0000x reference)
//
#include <hip/hip_runtime.h>
#include <hip/hip_bf16.h>
#include <hip/hip_fp16.h>

// GCN: x(N,4) -> GCNConv(4x16) relu -> GCNConv(16x32) relu -> FC(32x4)
// Aggregate-first (narrow) + dinv factorization.
// Build: k_zero -> k_bucket (rank-first: local rank during load, one LDS
// atomic pass; per-bucket span reservation; direct ranked global stores)
// -> k_sortpre (per-bucket LDS counting sort, rank-stores scattered-to-L2,
// no write-back pass). Aggregation: register gathers, multi-lane/node,
// unroll-4 batches, shfl reduce; fp16 feature tables (L2-resident).

#define NBUCK 1024
#define TILE  6144      // 12 edges/thread * 512 threads; 521 blocks
#define EPT   12
#define BSH   7         // 128 nodes per bucket
#define CAP   5120      // bucket capacity: mean ~4096, sigma ~64, +16 sigma

__global__ void k_zero(int* __restrict__ gcur) {
    gcur[blockIdx.x * 512 + threadIdx.x] = 0;
}

__global__ __launch_bounds__(512)
void k_bucket(const int* __restrict__ src, const int* __restrict__ dst,
              int* __restrict__ gcur, int* __restrict__ colbkt, int E) {
    __shared__ int wcur[NBUCK];
    __shared__ int base[NBUCK];
    int t = threadIdx.x;
    int tb = blockIdx.x * TILE;
    int cntT = min(TILE, E - tb);

    wcur[t] = 0; wcur[t + 512] = 0;
    __syncthreads();

    // single pass: load edges, rank locally (one LDS atomic per edge)
    int rec[EPT], bk[EPT], pos[EPT];
    #pragma unroll
    for (int j = 0; j < EPT; j++) {
        int i = t + j * 512;
        bool ok = i < cntT;
        int sv = ok ? src[tb + i] : 0;
        int dv = ok ? dst[tb + i] : 0;
        bk[j] = dv >> BSH;
        rec[j] = sv | ((dv & ((1 << BSH) - 1)) << 17);
        pos[j] = ok ? atomicAdd(&wcur[bk[j]], 1) : -1;
    }
    __syncthreads();

    // reserve this tile's span in each bucket (1 global atomic/bucket/tile)
    #pragma unroll
    for (int j = 0; j < NBUCK / 512; j++) {
        int b = t + j * 512;
        int c = wcur[b];
        base[b] = (c > 0) ? atomicAdd(&gcur[b], c) : 0;
    }
    __syncthreads();

    // direct global store; per-bucket runs are contiguous and temporally
    // clustered inside this block, so L2 merges them into full lines
    #pragma unroll
    for (int j = 0; j < EPT; j++) {
        if (pos[j] >= 0) {
            int idx = base[bk[j]] + pos[j];
            if (idx < CAP) colbkt[(size_t)bk[j] * CAP + idx] = rec[j];
        }
    }
}

// per bucket: LDS counting sort by dest-local node; rank-stores go directly
// to global (scattered within the bucket's ~20KB span -> L2-merged);
// emit rowbeg/rowlen per node; fused dinv + g1h = fp16(dinv .* x)
__global__ __launch_bounds__(256)
void k_sortpre(const int* __restrict__ gcur, int* __restrict__ colbkt,
               const float* __restrict__ x, float* __restrict__ dinv,
               __half* __restrict__ g1h, int* __restrict__ rowbeg,
               int* __restrict__ rowlen, int n) {
    __shared__ int recbuf[CAP];
    __shared__ int hist[128];
    __shared__ int offs[128];
    __shared__ int cur[128];
    __shared__ int wtot;
    int t = threadIdx.x, b = blockIdx.x;
    int nb = min(gcur[b], CAP);
    int* row = colbkt + (size_t)b * CAP;
    if (t < 128) hist[t] = 0;
    __syncthreads();
    for (int e = t; e < nb; e += 256) {
        int rec = __builtin_nontemporal_load(row + e);
        recbuf[e] = rec;
        atomicAdd(&hist[(rec >> 17) & 127], 1);
    }
    __syncthreads();
    // scan over 128 entries: 2 waves, shfl scan + wave-0 total
    int h = (t < 128) ? hist[t] : 0;
    int lane = t & 63;
    int incl = h;
    #pragma unroll
    for (int off = 1; off < 64; off <<= 1) {
        int v = __shfl_up(incl, off);
        if (lane >= off) incl += v;
    }
    if (t == 63) wtot = incl;
    __syncthreads();
    if (t < 128) {
        int incl2 = incl + ((t >= 64) ? wtot : 0);
        offs[t] = incl2;
        cur[t] = incl2 - h;
    }
    __syncthreads();
    // rank + direct scattered global store (L2 merges within bucket span)
    for (int e = t; e < nb; e += 256) {
        int rec = recbuf[e];
        int dl = (rec >> 17) & 127;
        int p = atomicAdd(&cur[dl], 1);
        row[p] = rec;
    }
    // per-node epilogue (independent of the rank loop; no barrier needed)
    if (t < 128) {
        int node = (b << BSH) + t;
        if (node < n) {
            int len = hist[t];
            rowlen[node] = len;
            rowbeg[node] = b * CAP + (offs[t] - len);
            float di = rsqrtf((float)len + 1.0f);
            dinv[node] = di;
            float4 xv = *reinterpret_cast<const float4*>(x + (size_t)node * 4);
            union { __half2 h2[2]; uint2 u2; } pk;
            pk.h2[0] = __floats2half2_rn(di * xv.x, di * xv.y);
            pk.h2[1] = __floats2half2_rn(di * xv.z, di * xv.w);
            *reinterpret_cast<uint2*>(g1h + (size_t)node * 4) = pk.u2;
        }
    }
}

__device__ __forceinline__ void add_g1(float& a0, float& a1, float& a2, float& a3,
                                       uint2 u) {
    float2 f0 = __half22float2(*reinterpret_cast<const __half2*>(&u.x));
    float2 f1 = __half22float2(*reinterpret_cast<const __half2*>(&u.y));
    a0 += f0.x; a1 += f0.y; a2 += f1.x; a3 += f1.y;
}

// 4 lanes per node, unroll-4 gather batches; fused lin1+relu; g2h=fp16(dinv*h1)
__global__ __launch_bounds__(256)
void k_gather1(const int* __restrict__ rowbeg, const int* __restrict__ rowlen,
               const int* __restrict__ colbkt, const __half* __restrict__ g1h,
               const float* __restrict__ dinv, const float* __restrict__ W1,
               const float* __restrict__ b1, __half* __restrict__ g2h, int n) {
    __shared__ float w[64];
    __shared__ float bb[16];
    if (threadIdx.x < 64) w[threadIdx.x] = W1[threadIdx.x];
    if (threadIdx.x >= 64 && threadIdx.x < 80) bb[threadIdx.x - 64] = b1[threadIdx.x - 64];
    __syncthreads();
    int gt = blockIdx.x * 256 + threadIdx.x;
    int i = gt >> 2;
    int lane = gt & 3;
    if (i >= n) return;
    int len = rowlen[i];
    const int* row = colbkt + rowbeg[i];
    const uint2* g1v = reinterpret_cast<const uint2*>(g1h);
    float a0 = 0.f, a1 = 0.f, a2 = 0.f, a3 = 0.f;
    if (lane == 0)   // self-loop term
        add_g1(a0, a1, a2, a3, g1v[i]);
    int e = lane;
    for (; e + 12 < len; e += 16) {
        int r0 = __builtin_nontemporal_load(row + e);
        int r1 = __builtin_nontemporal_load(row + e + 4);
        int r2 = __builtin_nontemporal_load(row + e + 8);
        int r3 = __builtin_nontemporal_load(row + e + 12);
        uint2 u0 = g1v[r0 & 0x1FFFF];
        uint2 u1 = g1v[r1 & 0x1FFFF];
        uint2 u2 = g1v[r2 & 0x1FFFF];
        uint2 u3 = g1v[r3 & 0x1FFFF];
        add_g1(a0, a1, a2, a3, u0);
        add_g1(a0, a1, a2, a3, u1);
        add_g1(a0, a1, a2, a3, u2);
        add_g1(a0, a1, a2, a3, u3);
    }
    for (; e < len; e += 4) {
        int rec = __builtin_nontemporal_load(row + e);
        add_g1(a0, a1, a2, a3, g1v[rec & 0x1FFFF]);
    }
    a0 += __shfl_xor(a0, 1); a1 += __shfl_xor(a1, 1);
    a2 += __shfl_xor(a2, 1); a3 += __shfl_xor(a3, 1);
    a0 += __shfl_xor(a0, 2); a1 += __shfl_xor(a1, 2);
    a2 += __shfl_xor(a2, 2); a3 += __shfl_xor(a3, 2);
    if (lane != 0) return;
    float di = dinv[i];
    a0 *= di; a1 *= di; a2 *= di; a3 *= di;
    union { __half2 h2[8]; uint4 u4[2]; } pk;
    #pragma unroll
    for (int c = 0; c < 8; c++) {
        int f0 = 2 * c, f1 = 2 * c + 1;
        float r0 = di * fmaxf(a0*w[f0] + a1*w[16+f0] + a2*w[32+f0] + a3*w[48+f0] + bb[f0], 0.f);
        float r1 = di * fmaxf(a0*w[f1] + a1*w[16+f1] + a2*w[32+f1] + a3*w[48+f1] + bb[f1], 0.f);
        pk.h2[c] = __floats2half2_rn(r0, r1);
    }
    uint4* o = reinterpret_cast<uint4*>(g2h + (size_t)i * 16);
    o[0] = pk.u4[0];
    o[1] = pk.u4[1];
}

__device__ __forceinline__ void add_g2(float* acc, uint4 a, uint4 b) {
    const __half2* pa = reinterpret_cast<const __half2*>(&a);
    const __half2* pb = reinterpret_cast<const __half2*>(&b);
    #pragma unroll
    for (int j = 0; j < 4; j++) {
        float2 f = __half22float2(pa[j]);
        acc[2*j] += f.x; acc[2*j+1] += f.y;
    }
    #pragma unroll
    for (int j = 0; j < 4; j++) {
        float2 f = __half22float2(pb[j]);
        acc[8+2*j] += f.x; acc[8+2*j+1] += f.y;
    }
}

// 8 lanes per node, unroll-4 gather batches (32 loads in flight per node),
// shfl butterfly reduce; lin2+relu+fc distributed 4 outputs/lane
__global__ __launch_bounds__(256)
void k_gather2(const int* __restrict__ rowbeg, const int* __restrict__ rowlen,
               const int* __restrict__ colbkt, const __half* __restrict__ g2h,
               const float* __restrict__ dinv, const float* __restrict__ W2,
               const float* __restrict__ b2, const float* __restrict__ Wfc,
               const float* __restrict__ bfc, float* __restrict__ out, int n) {
    __shared__ float w2[512];
    __shared__ float wf[128];
    __shared__ float b2s[32];
    __shared__ float bfs[4];
    for (int j = threadIdx.x; j < 512; j += blockDim.x) w2[j] = W2[j];
    if (threadIdx.x < 128) wf[threadIdx.x] = Wfc[threadIdx.x];
    if (threadIdx.x >= 128 && threadIdx.x < 160) b2s[threadIdx.x - 128] = b2[threadIdx.x - 128];
    if (threadIdx.x >= 160 && threadIdx.x < 164) bfs[threadIdx.x - 160] = bfc[threadIdx.x - 160];
    __syncthreads();

    int gt = blockIdx.x * 256 + threadIdx.x;
    int i = gt >> 3;
    int lane = gt & 7;
    if (i >= n) return;
    int len = rowlen[i];
    const int* row = colbkt + rowbeg[i];
    const uint4* g2v = reinterpret_cast<const uint4*>(g2h);

    float acc[16];
    #pragma unroll
    for (int k = 0; k < 16; k++) acc[k] = 0.f;
    if (lane == 0)   // self-loop term
        add_g2(acc, g2v[(size_t)i * 2], g2v[(size_t)i * 2 + 1]);
    int e = lane;
    for (; e + 24 < len; e += 32) {
        int r0 = __builtin_nontemporal_load(row + e);
        int r1 = __builtin_nontemporal_load(row + e + 8);
        int r2 = __builtin_nontemporal_load(row + e + 16);
        int r3 = __builtin_nontemporal_load(row + e + 24);
        size_t s0 = (size_t)(r0 & 0x1FFFF) * 2;
        size_t s1 = (size_t)(r1 & 0x1FFFF) * 2;
        size_t s2 = (size_t)(r2 & 0x1FFFF) * 2;
        size_t s3 = (size_t)(r3 & 0x1FFFF) * 2;
        uint4 a0 = g2v[s0], c0 = g2v[s0 + 1];
        uint4 a1 = g2v[s1], c1 = g2v[s1 + 1];
        uint4 a2 = g2v[s2], c2 = g2v[s2 + 1];
        uint4 a3 = g2v[s3], c3 = g2v[s3 + 1];
        add_g2(acc, a0, c0);
        add_g2(acc, a1, c1);
        add_g2(acc, a2, c2);
        add_g2(acc, a3, c3);
    }
    for (; e < len; e += 8) {
        int rec = __builtin_nontemporal_load(row + e);
        size_t s = (size_t)(rec & 0x1FFFF) * 2;
        add_g2(acc, g2v[s], g2v[s + 1]);
    }
    #pragma unroll
    for (int k = 0; k < 16; k++) acc[k] += __shfl_xor(acc[k], 1);
    #pragma unroll
    for (int k = 0; k < 16; k++) acc[k] += __shfl_xor(acc[k], 2);
    #pragma unroll
    for (int k = 0; k < 16; k++) acc[k] += __shfl_xor(acc[k], 4);

    float di = dinv[i];
    #pragma unroll
    for (int k = 0; k < 16; k++) acc[k] *= di;

    // distributed epilogue: each of 8 lanes does 4 of the 32 lin2 outputs
    float o0 = (lane == 0) ? bfs[0] : 0.f;
    float o1 = (lane == 0) ? bfs[1] : 0.f;
    float o2 = (lane == 0) ? bfs[2] : 0.f;
    float o3 = (lane == 0) ? bfs[3] : 0.f;
    int fbase = lane * 4;
    #pragma unroll
    for (int fo = 0; fo < 4; fo++) {
        int f = fbase + fo;
        float h = b2s[f];
        #pragma unroll
        for (int k = 0; k < 16; k++) h += acc[k] * w2[k * 32 + f];
        h = fmaxf(h, 0.0f);
        o0 += h * wf[f * 4 + 0];
        o1 += h * wf[f * 4 + 1];
        o2 += h * wf[f * 4 + 2];
        o3 += h * wf[f * 4 + 3];
    }
    o0 += __shfl_xor(o0, 1); o1 += __shfl_xor(o1, 1);
    o2 += __shfl_xor(o2, 1); o3 += __shfl_xor(o3, 1);
    o0 += __shfl_xor(o0, 2); o1 += __shfl_xor(o1, 2);
    o2 += __shfl_xor(o2, 2); o3 += __shfl_xor(o3, 2);
    o0 += __shfl_xor(o0, 4); o1 += __shfl_xor(o1, 4);
    o2 += __shfl_xor(o2, 4); o3 += __shfl_xor(o3, 4);
    if (lane != 0) return;
    float4 r; r.x = o0; r.y = o1; r.z = o2; r.w = o3;
    *reinterpret_cast<float4*>(out + (size_t)i * 4) = r;
}

extern "C" void kernel_launch(void* const* d_in, const int* in_sizes, int n_in,
                              void* d_out, int out_size, void* d_ws, size_t ws_size,
                              hipStream_t stream) {
    const float* x   = (const float*)d_in[0];
    const int*   ei  = (const int*)d_in[1];
    const float* W1  = (const float*)d_in[2];
    const float* b1  = (const float*)d_in[3];
    const float* W2  = (const float*)d_in[4];
    const float* b2  = (const float*)d_in[5];
    const float* Wfc = (const float*)d_in[6];
    const float* bfc = (const float*)d_in[7];
    float* out = (float*)d_out;

    const int n = in_sizes[0] / 4;      // 100000
    const int E = in_sizes[1] / 2;      // 3200000
    const int* src = ei;
    const int* dst = ei + E;

    char* p = (char*)d_ws;
    int*    gcur   = (int*)p;           p += (size_t)NBUCK * 4;
    int*    colbkt = (int*)p;           p += (size_t)NBUCK * CAP * 4;
    int*    rowbeg = (int*)p;           p += (size_t)n * 4;
    int*    rowlen = (int*)p;           p += (size_t)n * 4;
    float*  dinv   = (float*)p;         p += (size_t)n * 4;
    __half* g1h    = (__half*)p;        p += (size_t)n * 8;    // N x 4 fp16
    __half* g2h    = (__half*)p;        p += (size_t)n * 32;   // N x 16 fp16

    const int NBu = (n + 127) >> BSH;          // 782 buckets used
    const int gT  = (E + TILE - 1) / TILE;     // 521 tiles
    const int gN4 = ((size_t)n * 4 + 255) / 256;   // 4 lanes per node
    const int gN8 = ((size_t)n * 8 + 255) / 256;   // 8 lanes per node

    k_zero   <<<NBUCK / 512, 512, 0, stream>>>(gcur);
    k_bucket <<<gT,  512, 0, stream>>>(src, dst, gcur, colbkt, E);
    k_sortpre<<<NBu, 256, 0, stream>>>(gcur, colbkt, x, dinv, g1h, rowbeg, rowlen, n);
    k_gather1<<<gN4, 256, 0, stream>>>(rowbeg, rowlen, colbkt, g1h, dinv, W1, b1, g2h, n);
    k_gather2<<<gN8, 256, 0, stream>>>(rowbeg, rowlen, colbkt, g2h, dinv,
                                       W2, b2, Wfc, bfc, out, n);
}

// Round 14
// 123.135 us; speedup vs baseline: 1.0662x; 1.0662x over previous
//
#include <hip/hip_runtime.h>
#include <hip/hip_bf16.h>
#include <hip/hip_fp16.h>

// GCN: x(N,4) -> GCNConv(4x16) relu -> GCNConv(16x32) relu -> FC(32x4)
// Aggregate-first (narrow) + dinv factorization.
// Build: k_zero -> k_bucket (1024-thr: single-read hist-from-regs, per-bucket
// span reservation, rank + direct ranked global stores) -> k_sortpre (512-thr
// per-bucket LDS counting sort, scatter rank-stores L2-merged).
// Aggregation: register gathers, multi-lane/node, unroll-4, shfl reduce;
// fp16 feature tables (L2-resident).

#define NBUCK 1024
#define TILE  8192      // 8 edges/thread * 1024 threads; 391 blocks
#define EPT   8
#define BSH   7         // 128 nodes per bucket
#define CAP   5120      // bucket capacity: mean ~4096, sigma ~64, +16 sigma

__global__ void k_zero(int* __restrict__ gcur) {
    gcur[blockIdx.x * 512 + threadIdx.x] = 0;
}

__global__ __launch_bounds__(1024)
void k_bucket(const int* __restrict__ src, const int* __restrict__ dst,
              int* __restrict__ gcur, int* __restrict__ colbkt, int E) {
    __shared__ int hist[NBUCK];
    __shared__ int wcur[NBUCK];
    int t = threadIdx.x;
    int tb = blockIdx.x * TILE;
    int cntT = min(TILE, E - tb);

    hist[t] = 0;
    __syncthreads();

    // single global read: edges into registers (static indices), hist from regs
    int sv[EPT], dv[EPT];
    #pragma unroll
    for (int j = 0; j < EPT; j++) {
        int i = t + j * 1024;
        bool ok = i < cntT;
        sv[j] = ok ? src[tb + i] : 0;
        dv[j] = ok ? dst[tb + i] : 0;
        if (ok) atomicAdd(&hist[dv[j] >> BSH], 1);
    }
    __syncthreads();

    // reserve this tile's span in each bucket (1 global atomic/bucket/tile);
    // wcur[b] starts at the reserved global base
    {
        int c = hist[t];
        wcur[t] = (c > 0) ? atomicAdd(&gcur[t], c) : 0;
    }
    __syncthreads();

    // rank + direct global store; per-bucket runs are contiguous and
    // temporally clustered inside this block, so L2 merges them into lines
    #pragma unroll
    for (int j = 0; j < EPT; j++) {
        int i = t + j * 1024;
        if (i < cntT) {
            int b = dv[j] >> BSH;
            int pos = atomicAdd(&wcur[b], 1);
            if (pos < CAP)
                colbkt[(size_t)b * CAP + pos] =
                    sv[j] | ((dv[j] & ((1 << BSH) - 1)) << 17);
        }
    }
}

// per bucket: LDS counting sort by dest-local node; rank-stores go directly
// to global (scattered within the bucket's ~20KB span -> L2-merged);
// emit rowbeg/rowlen per node; fused dinv + g1h = fp16(dinv .* x)
__global__ __launch_bounds__(512)
void k_sortpre(const int* __restrict__ gcur, int* __restrict__ colbkt,
               const float* __restrict__ x, float* __restrict__ dinv,
               __half* __restrict__ g1h, int* __restrict__ rowbeg,
               int* __restrict__ rowlen, int n) {
    __shared__ int recbuf[CAP];
    __shared__ int hist[128];
    __shared__ int offs[128];
    __shared__ int cur[128];
    __shared__ int wtot;
    int t = threadIdx.x, b = blockIdx.x;
    int nb = min(gcur[b], CAP);
    int* row = colbkt + (size_t)b * CAP;
    if (t < 128) hist[t] = 0;
    __syncthreads();
    for (int e = t; e < nb; e += 512) {
        int rec = __builtin_nontemporal_load(row + e);
        recbuf[e] = rec;
        atomicAdd(&hist[(rec >> 17) & 127], 1);
    }
    __syncthreads();
    // scan over 128 entries: 2 waves, shfl scan + wave-0 total
    int h = (t < 128) ? hist[t] : 0;
    int lane = t & 63;
    int incl = h;
    #pragma unroll
    for (int off = 1; off < 64; off <<= 1) {
        int v = __shfl_up(incl, off);
        if (lane >= off) incl += v;
    }
    if (t == 63) wtot = incl;
    __syncthreads();
    if (t < 128) {
        int incl2 = incl + ((t >= 64) ? wtot : 0);
        offs[t] = incl2;
        cur[t] = incl2 - h;
    }
    __syncthreads();
    // rank + direct scattered global store (L2 merges within bucket span)
    for (int e = t; e < nb; e += 512) {
        int rec = recbuf[e];
        int dl = (rec >> 17) & 127;
        int p = atomicAdd(&cur[dl], 1);
        row[p] = rec;
    }
    // per-node epilogue (independent of the rank loop; no barrier needed)
    if (t < 128) {
        int node = (b << BSH) + t;
        if (node < n) {
            int len = hist[t];
            rowlen[node] = len;
            rowbeg[node] = b * CAP + (offs[t] - len);
            float di = rsqrtf((float)len + 1.0f);
            dinv[node] = di;
            float4 xv = *reinterpret_cast<const float4*>(x + (size_t)node * 4);
            union { __half2 h2[2]; uint2 u2; } pk;
            pk.h2[0] = __floats2half2_rn(di * xv.x, di * xv.y);
            pk.h2[1] = __floats2half2_rn(di * xv.z, di * xv.w);
            *reinterpret_cast<uint2*>(g1h + (size_t)node * 4) = pk.u2;
        }
    }
}

__device__ __forceinline__ void add_g1(float& a0, float& a1, float& a2, float& a3,
                                       uint2 u) {
    float2 f0 = __half22float2(*reinterpret_cast<const __half2*>(&u.x));
    float2 f1 = __half22float2(*reinterpret_cast<const __half2*>(&u.y));
    a0 += f0.x; a1 += f0.y; a2 += f1.x; a3 += f1.y;
}

// 4 lanes per node, unroll-4 gather batches; fused lin1+relu; g2h=fp16(dinv*h1)
__global__ __launch_bounds__(256)
void k_gather1(const int* __restrict__ rowbeg, const int* __restrict__ rowlen,
               const int* __restrict__ colbkt, const __half* __restrict__ g1h,
               const float* __restrict__ dinv, const float* __restrict__ W1,
               const float* __restrict__ b1, __half* __restrict__ g2h, int n) {
    __shared__ float w[64];
    __shared__ float bb[16];
    if (threadIdx.x < 64) w[threadIdx.x] = W1[threadIdx.x];
    if (threadIdx.x >= 64 && threadIdx.x < 80) bb[threadIdx.x - 64] = b1[threadIdx.x - 64];
    __syncthreads();
    int gt = blockIdx.x * 256 + threadIdx.x;
    int i = gt >> 2;
    int lane = gt & 3;
    if (i >= n) return;
    int len = rowlen[i];
    const int* row = colbkt + rowbeg[i];
    const uint2* g1v = reinterpret_cast<const uint2*>(g1h);
    float a0 = 0.f, a1 = 0.f, a2 = 0.f, a3 = 0.f;
    if (lane == 0)   // self-loop term
        add_g1(a0, a1, a2, a3, g1v[i]);
    int e = lane;
    for (; e + 12 < len; e += 16) {
        int r0 = __builtin_nontemporal_load(row + e);
        int r1 = __builtin_nontemporal_load(row + e + 4);
        int r2 = __builtin_nontemporal_load(row + e + 8);
        int r3 = __builtin_nontemporal_load(row + e + 12);
        uint2 u0 = g1v[r0 & 0x1FFFF];
        uint2 u1 = g1v[r1 & 0x1FFFF];
        uint2 u2 = g1v[r2 & 0x1FFFF];
        uint2 u3 = g1v[r3 & 0x1FFFF];
        add_g1(a0, a1, a2, a3, u0);
        add_g1(a0, a1, a2, a3, u1);
        add_g1(a0, a1, a2, a3, u2);
        add_g1(a0, a1, a2, a3, u3);
    }
    for (; e < len; e += 4) {
        int rec = __builtin_nontemporal_load(row + e);
        add_g1(a0, a1, a2, a3, g1v[rec & 0x1FFFF]);
    }
    a0 += __shfl_xor(a0, 1); a1 += __shfl_xor(a1, 1);
    a2 += __shfl_xor(a2, 1); a3 += __shfl_xor(a3, 1);
    a0 += __shfl_xor(a0, 2); a1 += __shfl_xor(a1, 2);
    a2 += __shfl_xor(a2, 2); a3 += __shfl_xor(a3, 2);
    if (lane != 0) return;
    float di = dinv[i];
    a0 *= di; a1 *= di; a2 *= di; a3 *= di;
    union { __half2 h2[8]; uint4 u4[2]; } pk;
    #pragma unroll
    for (int c = 0; c < 8; c++) {
        int f0 = 2 * c, f1 = 2 * c + 1;
        float r0 = di * fmaxf(a0*w[f0] + a1*w[16+f0] + a2*w[32+f0] + a3*w[48+f0] + bb[f0], 0.f);
        float r1 = di * fmaxf(a0*w[f1] + a1*w[16+f1] + a2*w[32+f1] + a3*w[48+f1] + bb[f1], 0.f);
        pk.h2[c] = __floats2half2_rn(r0, r1);
    }
    uint4* o = reinterpret_cast<uint4*>(g2h + (size_t)i * 16);
    o[0] = pk.u4[0];
    o[1] = pk.u4[1];
}

__device__ __forceinline__ void add_g2(float* acc, uint4 a, uint4 b) {
    const __half2* pa = reinterpret_cast<const __half2*>(&a);
    const __half2* pb = reinterpret_cast<const __half2*>(&b);
    #pragma unroll
    for (int j = 0; j < 4; j++) {
        float2 f = __half22float2(pa[j]);
        acc[2*j] += f.x; acc[2*j+1] += f.y;
    }
    #pragma unroll
    for (int j = 0; j < 4; j++) {
        float2 f = __half22float2(pb[j]);
        acc[8+2*j] += f.x; acc[8+2*j+1] += f.y;
    }
}

// 8 lanes per node, unroll-4 gather batches (32 loads in flight per node),
// shfl butterfly reduce; lin2+relu+fc distributed 4 outputs/lane
__global__ __launch_bounds__(256)
void k_gather2(const int* __restrict__ rowbeg, const int* __restrict__ rowlen,
               const int* __restrict__ colbkt, const __half* __restrict__ g2h,
               const float* __restrict__ dinv, const float* __restrict__ W2,
               const float* __restrict__ b2, const float* __restrict__ Wfc,
               const float* __restrict__ bfc, float* __restrict__ out, int n) {
    __shared__ float w2[512];
    __shared__ float wf[128];
    __shared__ float b2s[32];
    __shared__ float bfs[4];
    for (int j = threadIdx.x; j < 512; j += blockDim.x) w2[j] = W2[j];
    if (threadIdx.x < 128) wf[threadIdx.x] = Wfc[threadIdx.x];
    if (threadIdx.x >= 128 && threadIdx.x < 160) b2s[threadIdx.x - 128] = b2[threadIdx.x - 128];
    if (threadIdx.x >= 160 && threadIdx.x < 164) bfs[threadIdx.x - 160] = bfc[threadIdx.x - 160];
    __syncthreads();

    int gt = blockIdx.x * 256 + threadIdx.x;
    int i = gt >> 3;
    int lane = gt & 7;
    if (i >= n) return;
    int len = rowlen[i];
    const int* row = colbkt + rowbeg[i];
    const uint4* g2v = reinterpret_cast<const uint4*>(g2h);

    float acc[16];
    #pragma unroll
    for (int k = 0; k < 16; k++) acc[k] = 0.f;
    if (lane == 0)   // self-loop term
        add_g2(acc, g2v[(size_t)i * 2], g2v[(size_t)i * 2 + 1]);
    int e = lane;
    for (; e + 24 < len; e += 32) {
        int r0 = __builtin_nontemporal_load(row + e);
        int r1 = __builtin_nontemporal_load(row + e + 8);
        int r2 = __builtin_nontemporal_load(row + e + 16);
        int r3 = __builtin_nontemporal_load(row + e + 24);
        size_t s0 = (size_t)(r0 & 0x1FFFF) * 2;
        size_t s1 = (size_t)(r1 & 0x1FFFF) * 2;
        size_t s2 = (size_t)(r2 & 0x1FFFF) * 2;
        size_t s3 = (size_t)(r3 & 0x1FFFF) * 2;
        uint4 a0 = g2v[s0], c0 = g2v[s0 + 1];
        uint4 a1 = g2v[s1], c1 = g2v[s1 + 1];
        uint4 a2 = g2v[s2], c2 = g2v[s2 + 1];
        uint4 a3 = g2v[s3], c3 = g2v[s3 + 1];
        add_g2(acc, a0, c0);
        add_g2(acc, a1, c1);
        add_g2(acc, a2, c2);
        add_g2(acc, a3, c3);
    }
    for (; e < len; e += 8) {
        int rec = __builtin_nontemporal_load(row + e);
        size_t s = (size_t)(rec & 0x1FFFF) * 2;
        add_g2(acc, g2v[s], g2v[s + 1]);
    }
    #pragma unroll
    for (int k = 0; k < 16; k++) acc[k] += __shfl_xor(acc[k], 1);
    #pragma unroll
    for (int k = 0; k < 16; k++) acc[k] += __shfl_xor(acc[k], 2);
    #pragma unroll
    for (int k = 0; k < 16; k++) acc[k] += __shfl_xor(acc[k], 4);

    float di = dinv[i];
    #pragma unroll
    for (int k = 0; k < 16; k++) acc[k] *= di;

    // distributed epilogue: each of 8 lanes does 4 of the 32 lin2 outputs
    float o0 = (lane == 0) ? bfs[0] : 0.f;
    float o1 = (lane == 0) ? bfs[1] : 0.f;
    float o2 = (lane == 0) ? bfs[2] : 0.f;
    float o3 = (lane == 0) ? bfs[3] : 0.f;
    int fbase = lane * 4;
    #pragma unroll
    for (int fo = 0; fo < 4; fo++) {
        int f = fbase + fo;
        float h = b2s[f];
        #pragma unroll
        for (int k = 0; k < 16; k++) h += acc[k] * w2[k * 32 + f];
        h = fmaxf(h, 0.0f);
        o0 += h * wf[f * 4 + 0];
        o1 += h * wf[f * 4 + 1];
        o2 += h * wf[f * 4 + 2];
        o3 += h * wf[f * 4 + 3];
    }
    o0 += __shfl_xor(o0, 1); o1 += __shfl_xor(o1, 1);
    o2 += __shfl_xor(o2, 1); o3 += __shfl_xor(o3, 1);
    o0 += __shfl_xor(o0, 2); o1 += __shfl_xor(o1, 2);
    o2 += __shfl_xor(o2, 2); o3 += __shfl_xor(o3, 2);
    o0 += __shfl_xor(o0, 4); o1 += __shfl_xor(o1, 4);
    o2 += __shfl_xor(o2, 4); o3 += __shfl_xor(o3, 4);
    if (lane != 0) return;
    float4 r; r.x = o0; r.y = o1; r.z = o2; r.w = o3;
    *reinterpret_cast<float4*>(out + (size_t)i * 4) = r;
}

extern "C" void kernel_launch(void* const* d_in, const int* in_sizes, int n_in,
                              void* d_out, int out_size, void* d_ws, size_t ws_size,
                              hipStream_t stream) {
    const float* x   = (const float*)d_in[0];
    const int*   ei  = (const int*)d_in[1];
    const float* W1  = (const float*)d_in[2];
    const float* b1  = (const float*)d_in[3];
    const float* W2  = (const float*)d_in[4];
    const float* b2  = (const float*)d_in[5];
    const float* Wfc = (const float*)d_in[6];
    const float* bfc = (const float*)d_in[7];
    float* out = (float*)d_out;

    const int n = in_sizes[0] / 4;      // 100000
    const int E = in_sizes[1] / 2;      // 3200000
    const int* src = ei;
    const int* dst = ei + E;

    char* p = (char*)d_ws;
    int*    gcur   = (int*)p;           p += (size_t)NBUCK * 4;
    int*    colbkt = (int*)p;           p += (size_t)NBUCK * CAP * 4;
    int*    rowbeg = (int*)p;           p += (size_t)n * 4;
    int*    rowlen = (int*)p;           p += (size_t)n * 4;
    float*  dinv   = (float*)p;         p += (size_t)n * 4;
    __half* g1h    = (__half*)p;        p += (size_t)n * 8;    // N x 4 fp16
    __half* g2h    = (__half*)p;        p += (size_t)n * 32;   // N x 16 fp16

    const int NBu = (n + 127) >> BSH;          // 782 buckets used
    const int gT  = (E + TILE - 1) / TILE;     // 391 tiles
    const int gN4 = ((size_t)n * 4 + 255) / 256;   // 4 lanes per node
    const int gN8 = ((size_t)n * 8 + 255) / 256;   // 8 lanes per node

    k_zero   <<<NBUCK / 512, 512, 0, stream>>>(gcur);
    k_bucket <<<gT,  1024, 0, stream>>>(src, dst, gcur, colbkt, E);
    k_sortpre<<<NBu, 512, 0, stream>>>(gcur, colbkt, x, dinv, g1h, rowbeg, rowlen, n);
    k_gather1<<<gN4, 256, 0, stream>>>(rowbeg, rowlen, colbkt, g1h, dinv, W1, b1, g2h, n);
    k_gather2<<<gN8, 256, 0, stream>>>(rowbeg, rowlen, colbkt, g2h, dinv,
                                       W2, b2, Wfc, bfc, out, n);
}